// Round 1
// baseline (67.431 us; speedup 1.0000x reference)
//
#include <hip/hip_runtime.h>
#include <math.h>

#define NB 4
#define NS 8192
#define ND 2048
#define NK 4096   // int(0.5 * NS)

// ---------------- Kernel 1: matvec + sigmoid ----------------
// one block (256 threads) per token; each thread handles 8 floats (2x float4)
__global__ void __launch_bounds__(256)
router_matvec(const float* __restrict__ hidden,
              const float* __restrict__ w,
              const float* __restrict__ bias,
              float* __restrict__ probs)
{
    const int token = blockIdx.x;                  // 0 .. NB*NS-1
    const float* hp = hidden + (size_t)token * ND;
    const int t = threadIdx.x;

    float acc = 0.0f;
#pragma unroll
    for (int j = 0; j < 2; ++j) {
        const int idx = (j * 256 + t) * 4;         // lane-contiguous float4
        const float4 h  = *reinterpret_cast<const float4*>(hp + idx);
        const float4 ww = *reinterpret_cast<const float4*>(w + idx);
        acc += h.x * ww.x + h.y * ww.y + h.z * ww.z + h.w * ww.w;
    }

    // wave (64-lane) reduce
#pragma unroll
    for (int off = 32; off; off >>= 1) acc += __shfl_down(acc, off, 64);

    __shared__ float lds[4];
    const int wid = t >> 6, lane = t & 63;
    if (lane == 0) lds[wid] = acc;
    __syncthreads();
    if (t == 0) {
        const float logit = lds[0] + lds[1] + lds[2] + lds[3] + bias[0];
        probs[token] = 1.0f / (1.0f + expf(-logit));
    }
}

// ---------------- Kernel 2: per-row top-k mask + aux loss ----------------
// one block of 1024 threads per batch row; each thread owns 8 consecutive probs

__device__ __forceinline__ int block_reduce_int(int v, int* lds)
{
#pragma unroll
    for (int off = 32; off; off >>= 1) v += __shfl_down(v, off, 64);
    const int wid = threadIdx.x >> 6, lane = threadIdx.x & 63;
    __syncthreads();                 // protect lds from any previous use
    if (lane == 0) lds[wid] = v;
    __syncthreads();
    int s = 0;
#pragma unroll
    for (int i = 0; i < 16; ++i) s += lds[i];   // every thread: uniform broadcast sum
    return s;
}

__device__ __forceinline__ float block_reduce_float(float v, float* lds)
{
#pragma unroll
    for (int off = 32; off; off >>= 1) v += __shfl_down(v, off, 64);
    const int wid = threadIdx.x >> 6, lane = threadIdx.x & 63;
    __syncthreads();
    if (lane == 0) lds[wid] = v;
    __syncthreads();
    float s = 0.0f;
#pragma unroll
    for (int i = 0; i < 16; ++i) s += lds[i];
    return s;
}

__global__ void __launch_bounds__(1024)
topk_mask(const float* __restrict__ probs,
          float* __restrict__ mask,
          float* __restrict__ aux)
{
    const int b = blockIdx.x;
    const float* row = probs + b * NS;
    float*      mrow = mask  + b * NS;

    const int t = threadIdx.x;
    const int base = t * 8;
    const int wid = t >> 6, lane = t & 63;

    __shared__ int   ilds[16];
    __shared__ float flds[16];

    float    v[8];
    unsigned u[8];
#pragma unroll
    for (int i = 0; i < 8; ++i) {
        v[i] = row[base + i];
        u[i] = __float_as_uint(v[i]);   // sigmoid > 0 => uint order == float order
    }

    // ---- row sum (deterministic) for aux loss ----
    float s = 0.0f;
#pragma unroll
    for (int i = 0; i < 8; ++i) s += v[i];
    const float rowsum = block_reduce_float(s, flds);

    // ---- radix select: bit pattern of the NK-th largest value ----
    unsigned prefix = 0;
    int kk = NK;                 // how many still needed within current prefix group
#pragma unroll
    for (int bit = 31; bit >= 0; --bit) {
        const unsigned cand = prefix | (1u << bit);
        const unsigned hm   = ~((1u << bit) - 1u);   // keep bits [31..bit]
        int c = 0;
#pragma unroll
        for (int i = 0; i < 8; ++i) c += ((u[i] & hm) == cand) ? 1 : 0;
        const int tot = block_reduce_int(c, ilds);
        if (tot >= kk) prefix = cand;
        else           kk -= tot;
    }
    const unsigned thr = prefix;   // exact bits of threshold value T
    const int need_ties = kk;      // # elements equal to T to take (lowest index first)

    // ---- exclusive scan of per-element "== T" counts in global index order ----
    int eqc = 0;
#pragma unroll
    for (int i = 0; i < 8; ++i) eqc += (u[i] == thr) ? 1 : 0;

    int inc = eqc;                 // wave-level inclusive scan
#pragma unroll
    for (int off = 1; off < 64; off <<= 1) {
        const int y = __shfl_up(inc, off, 64);
        if (lane >= off) inc += y;
    }
    __syncthreads();               // protect ilds from reduce reads above
    if (lane == 63) ilds[wid] = inc;
    __syncthreads();
    if (t == 0) {
        int run = 0;
#pragma unroll
        for (int wv = 0; wv < 16; ++wv) { const int x = ilds[wv]; ilds[wv] = run; run += x; }
    }
    __syncthreads();
    int run = (inc - eqc) + ilds[wid];   // exclusive prefix of equals before my first elem

    // ---- write mask ----
#pragma unroll
    for (int i = 0; i < 8; ++i) {
        float m;
        if (u[i] > thr)       m = 1.0f;
        else if (u[i] == thr) { m = (run < need_ties) ? 1.0f : 0.0f; ++run; }
        else                  m = 0.0f;
        mrow[base + i] = m;
    }

    // ---- aux loss ----
    if (t == 0) {
        const float mean = rowsum * (1.0f / (float)NS);
        const float d = mean - 0.5f;
        aux[b] = 0.01f * d * d;
    }
}

extern "C" void kernel_launch(void* const* d_in, const int* in_sizes, int n_in,
                              void* d_out, int out_size, void* d_ws, size_t ws_size,
                              hipStream_t stream)
{
    const float* hidden = (const float*)d_in[0];   // [NB, NS, ND] f32
    const float* w      = (const float*)d_in[1];   // [ND] f32
    const float* bias   = (const float*)d_in[2];   // scalar f32

    float* out   = (float*)d_out;
    float* probs = out;                 // [NB, NS]
    float* mask  = out + NB * NS;       // [NB, NS]
    float* aux   = out + 2 * NB * NS;   // [NB]

    router_matvec<<<NB * NS, 256, 0, stream>>>(hidden, w, bias, probs);
    topk_mask<<<NB, 1024, 0, stream>>>(probs, mask, aux);
}